// Round 2
// baseline (178.448 us; speedup 1.0000x reference)
//
#include <hip/hip_runtime.h>
#include <hip/hip_bf16.h>
#include <stdint.h>

#define T_DIM 4096
#define H_DIM 1024
#define I_DIM 2048

typedef __bf16 bf16x8 __attribute__((ext_vector_type(8)));
typedef float f32x4 __attribute__((ext_vector_type(4)));
typedef unsigned short ushort_t;
typedef unsigned short us4 __attribute__((ext_vector_type(4)));

__device__ __forceinline__ unsigned short f32_to_bf16(float f) {
  unsigned int u = __float_as_uint(f);
  u += 0x7fffu + ((u >> 16) & 1u);  // RNE
  return (unsigned short)(u >> 16);
}

__device__ __forceinline__ void gload_lds16(const void* g, void* l) {
  __builtin_amdgcn_global_load_lds(
      (__attribute__((address_space(1))) void*)(uintptr_t)g,
      (__attribute__((address_space(3))) void*)(unsigned int)(uintptr_t)l,
      16, 0, 0);
}

#define S_BARRIER() asm volatile("s_barrier" ::: "memory")
#define WAITV(n) asm volatile("s_waitcnt vmcnt(" #n ")" ::: "memory")
#define IRFENCE() asm volatile("" ::: "memory")
#define MFMA16(acc, va, vb) \
  acc = __builtin_amdgcn_mfma_f32_16x16x32_bf16(va, vb, acc, 0, 0, 0)

// ---------------- rmsnorm: x[T][H] f32 -> normed bf16 ----------------
__global__ __launch_bounds__(256) void k_rmsnorm(const float* __restrict__ x,
                                                 const float* __restrict__ scale,
                                                 ushort_t* __restrict__ normed) {
  const int row = blockIdx.x, tid = threadIdx.x;
  const float4 v = ((const float4*)(x + (size_t)row * H_DIM))[tid];
  float ss = v.x * v.x + v.y * v.y + v.z * v.z + v.w * v.w;
#pragma unroll
  for (int off = 32; off > 0; off >>= 1) ss += __shfl_xor(ss, off);
  __shared__ float wsum[4];
  if ((tid & 63) == 0) wsum[tid >> 6] = ss;
  __syncthreads();
  const float tot = wsum[0] + wsum[1] + wsum[2] + wsum[3];
  const float inv = rsqrtf(tot * (1.0f / H_DIM) + 1e-5f);
  const float4 sc = ((const float4*)scale)[tid];
  us4 o;
  o.x = f32_to_bf16(v.x * inv * sc.x);
  o.y = f32_to_bf16(v.y * inv * sc.y);
  o.z = f32_to_bf16(v.z * inv * sc.z);
  o.w = f32_to_bf16(v.w * inv * sc.w);
  ((us4*)(normed + (size_t)row * H_DIM))[tid] = o;
}

// ------- transpose+convert: src[R][C] f32 -> dst[C][R] bf16 (per blockIdx.z) -------
__global__ __launch_bounds__(256) void k_transpose_cvt(const float* __restrict__ src,
                                                       ushort_t* __restrict__ dst,
                                                       int R, int C) {
  __shared__ float tile[32][33];
  const size_t eoff = (size_t)blockIdx.z * (size_t)R * (size_t)C;
  src += eoff;
  dst += eoff;
  const int x0 = blockIdx.x * 32, y0 = blockIdx.y * 32;
  const int tx = threadIdx.x & 31, ty = threadIdx.x >> 5;
#pragma unroll
  for (int i = 0; i < 4; ++i)
    tile[ty + 8 * i][tx] = src[(size_t)(y0 + ty + 8 * i) * C + x0 + tx];
  __syncthreads();
#pragma unroll
  for (int i = 0; i < 4; ++i)
    dst[(size_t)(x0 + ty + 8 * i) * R + y0 + tx] = f32_to_bf16(tile[tx][ty + 8 * i]);
}

// ---------------- out init: out = x + 0.5*(b2[0]+b2[1]) ----------------
__global__ __launch_bounds__(256) void k_init_out(const float* __restrict__ x,
                                                  const float* __restrict__ b2,
                                                  float* __restrict__ out) {
  const int idx = blockIdx.x * 256 + threadIdx.x;  // over T*H/4
  const int col4 = idx & (H_DIM / 4 - 1);
  const float4 xv = ((const float4*)x)[idx];
  const float4 b0 = ((const float4*)b2)[col4];
  const float4 b1 = ((const float4*)(b2 + H_DIM))[col4];
  float4 o;
  o.x = xv.x + 0.5f * (b0.x + b1.x);
  o.y = xv.y + 0.5f * (b0.y + b1.y);
  o.z = xv.z + 0.5f * (b0.z + b1.z);
  o.w = xv.w + 0.5f * (b0.w + b1.w);
  ((float4*)out)[idx] = o;
}

// ---------------- GEMM1 8-phase: act = act_fn(normed @ W1 + b1) ----------------
// Tile: 256 rows x 128 cols (gate AND linear, shared A). BK=64 as 2 k-half units.
// LDS units per dbuf: u0=A_k0[256][32], u1={Bg_k0[128][32],Bl_k0[128][32]}, u2=A_k1, u3=B_k1.
__global__ __launch_bounds__(512, 2) void k_gemm1_8ph(
    const ushort_t* __restrict__ normed, const ushort_t* __restrict__ w1T,
    const float* __restrict__ b1, ushort_t* __restrict__ act) {
  __shared__ __align__(16) ushort_t lds[2][4][8192];  // 128 KiB
  const int tid = threadIdx.x;
  const int wg = (blockIdx.x & 7) * 64 + (blockIdx.x >> 3);  // XCD swizzle (512%8==0)
  const int e = wg >> 8;
  const int rem = wg & 255;
  const int brow = (rem >> 4) * 256;
  const int bcol = (rem & 15) * 128;
  const int lane = tid & 63;
  const int wm = (tid >> 6) >> 1;  // 0..3
  const int wn = (tid >> 6) & 1;   // 0..1
  const int r16 = lane & 15, kh = lane >> 4;

  const ushort_t* aBase = normed + (size_t)brow * H_DIM;
  const ushort_t* gBase = w1T + ((size_t)e * 2 * I_DIM + bcol) * H_DIM;
  const ushort_t* lBase = gBase + (size_t)I_DIM * H_DIM;

  f32x4 accg[4][4], accl[4][4];
  const f32x4 zf = {0.f, 0.f, 0.f, 0.f};
#pragma unroll
  for (int m = 0; m < 4; ++m)
#pragma unroll
    for (int n = 0; n < 4; ++n) { accg[m][n] = zf; accl[m][n] = zf; }

  auto stageA = [&](int buf, int ksub, int kt) {
#pragma unroll
    for (int j = 0; j < 2; ++j) {
      const int row = j * 128 + (tid >> 2);
      const int col = (tid & 3) * 8;
      gload_lds16(aBase + (size_t)row * H_DIM + kt * 64 + ksub * 32 + col,
                  &lds[buf][ksub * 2][(j * 512 + (tid & ~63)) * 8]);
    }
  };
  auto stageB = [&](int buf, int ksub, int kt) {
    const int row = tid >> 2;
    const int kc = kt * 64 + ksub * 32 + (tid & 3) * 8;
    gload_lds16(gBase + (size_t)row * H_DIM + kc,
                &lds[buf][ksub * 2 + 1][(tid & ~63) * 8]);
    gload_lds16(lBase + (size_t)row * H_DIM + kc,
                &lds[buf][ksub * 2 + 1][4096 + (tid & ~63) * 8]);
  };
  auto rdA = [&](int buf, int ksub, int m) -> bf16x8 {
    const int r = wm * 64 + m * 16 + r16;
    return *(const bf16x8*)&lds[buf][ksub * 2][r * 32 + kh * 8];
  };
  auto rdBg = [&](int buf, int ksub, int n) -> bf16x8 {
    const int r = wn * 64 + n * 16 + r16;
    return *(const bf16x8*)&lds[buf][ksub * 2 + 1][r * 32 + kh * 8];
  };
  auto rdBl = [&](int buf, int ksub, int n) -> bf16x8 {
    const int r = wn * 64 + n * 16 + r16;
    return *(const bf16x8*)&lds[buf][ksub * 2 + 1][4096 + r * 32 + kh * 8];
  };

  // Prologue: tile 0, units in order u0,u1,u2,u3 (order pinned by IR fences).
  stageA(0, 0, 0); IRFENCE();
  stageB(0, 0, 0); IRFENCE();
  stageA(0, 1, 0); IRFENCE();
  stageB(0, 1, 0);
  WAITV(4);      // u0,u1 of tile 0 landed
  S_BARRIER();

  bf16x8 a[4], b[4];
#pragma unroll 1
  for (int t = 0; t < 15; ++t) {
    const int cur = t & 1, nxt = cur ^ 1;
    // -- ph0: gate, ksub0 (reads u0,u1; stages u0 of t+1)
#pragma unroll
    for (int m = 0; m < 4; ++m) a[m] = rdA(cur, 0, m);
#pragma unroll
    for (int n = 0; n < 4; ++n) b[n] = rdBg(cur, 0, n);
    stageA(nxt, 0, t + 1);
    S_BARRIER();
    __builtin_amdgcn_s_setprio(1);
#pragma unroll
    for (int m = 0; m < 4; ++m)
#pragma unroll
      for (int n = 0; n < 4; ++n) MFMA16(accg[m][n], a[m], b[n]);
    __builtin_amdgcn_s_setprio(0);
    WAITV(6);
    S_BARRIER();
    __builtin_amdgcn_sched_barrier(0);
    // -- ph1: linear, ksub0 (reads u1; reuses a; stages u1)
#pragma unroll
    for (int n = 0; n < 4; ++n) b[n] = rdBl(cur, 0, n);
    stageB(nxt, 0, t + 1);
    S_BARRIER();
    __builtin_amdgcn_s_setprio(1);
#pragma unroll
    for (int m = 0; m < 4; ++m)
#pragma unroll
      for (int n = 0; n < 4; ++n) MFMA16(accl[m][n], a[m], b[n]);
    __builtin_amdgcn_s_setprio(0);
    WAITV(4);
    S_BARRIER();
    __builtin_amdgcn_sched_barrier(0);
    // -- ph2: gate, ksub1 (reads u2,u3; stages u2)
#pragma unroll
    for (int m = 0; m < 4; ++m) a[m] = rdA(cur, 1, m);
#pragma unroll
    for (int n = 0; n < 4; ++n) b[n] = rdBg(cur, 1, n);
    stageA(nxt, 1, t + 1);
    S_BARRIER();
    __builtin_amdgcn_s_setprio(1);
#pragma unroll
    for (int m = 0; m < 4; ++m)
#pragma unroll
      for (int n = 0; n < 4; ++n) MFMA16(accg[m][n], a[m], b[n]);
    __builtin_amdgcn_s_setprio(0);
    WAITV(6);
    S_BARRIER();
    __builtin_amdgcn_sched_barrier(0);
    // -- ph3: linear, ksub1 (reads u3; stages u3)
#pragma unroll
    for (int n = 0; n < 4; ++n) b[n] = rdBl(cur, 1, n);
    stageB(nxt, 1, t + 1);
    S_BARRIER();
    __builtin_amdgcn_s_setprio(1);
#pragma unroll
    for (int m = 0; m < 4; ++m)
#pragma unroll
      for (int n = 0; n < 4; ++n) MFMA16(accl[m][n], a[m], b[n]);
    __builtin_amdgcn_s_setprio(0);
    WAITV(4);
    S_BARRIER();
    __builtin_amdgcn_sched_barrier(0);
  }
  // Tail tile t=15 in buf 1 (no staging).
  {
#pragma unroll
    for (int m = 0; m < 4; ++m) a[m] = rdA(1, 0, m);
#pragma unroll
    for (int n = 0; n < 4; ++n) b[n] = rdBg(1, 0, n);
#pragma unroll
    for (int m = 0; m < 4; ++m)
#pragma unroll
      for (int n = 0; n < 4; ++n) MFMA16(accg[m][n], a[m], b[n]);
#pragma unroll
    for (int n = 0; n < 4; ++n) b[n] = rdBl(1, 0, n);
#pragma unroll
    for (int m = 0; m < 4; ++m)
#pragma unroll
      for (int n = 0; n < 4; ++n) MFMA16(accl[m][n], a[m], b[n]);
    WAITV(0);
    S_BARRIER();
#pragma unroll
    for (int m = 0; m < 4; ++m) a[m] = rdA(1, 1, m);
#pragma unroll
    for (int n = 0; n < 4; ++n) b[n] = rdBg(1, 1, n);
#pragma unroll
    for (int m = 0; m < 4; ++m)
#pragma unroll
      for (int n = 0; n < 4; ++n) MFMA16(accg[m][n], a[m], b[n]);
#pragma unroll
    for (int n = 0; n < 4; ++n) b[n] = rdBl(1, 1, n);
#pragma unroll
    for (int m = 0; m < 4; ++m)
#pragma unroll
      for (int n = 0; n < 4; ++n) MFMA16(accl[m][n], a[m], b[n]);
  }

  // Epilogue: bias + clip + gelu-ish gate, store bf16 act.
  const float* b1e = b1 + (size_t)e * 2 * I_DIM;
#pragma unroll
  for (int m = 0; m < 4; ++m)
#pragma unroll
    for (int n = 0; n < 4; ++n) {
      const int gcol = bcol + wn * 64 + n * 16 + r16;
      const float bgb = b1e[gcol];
      const float blb = b1e[I_DIM + gcol];
#pragma unroll
      for (int rr = 0; rr < 4; ++rr) {
        const int grow = brow + wm * 64 + m * 16 + kh * 4 + rr;
        const float hg = accg[m][n][rr] + bgb;
        const float hl = accl[m][n][rr] + blb;
        const float g = fminf(hg, 7.f);
        const float l = fminf(fmaxf(hl, -7.f), 7.f);
        const float s = 1.f / (1.f + __expf(-1.702f * g));
        const float av = g * s * (l + 1.f);
        act[((size_t)e * T_DIM + grow) * I_DIM + gcol] = f32_to_bf16(av);
      }
    }
}

// ---------------- GEMM2 8-phase, split-K=4 (expert x I-half), atomic epilogue ----
__global__ __launch_bounds__(512, 2) void k_gemm2_8ph(
    const ushort_t* __restrict__ act, const ushort_t* __restrict__ w2T,
    float* __restrict__ out) {
  __shared__ __align__(16) ushort_t lds[2][4][8192];
  const int tid = threadIdx.x;
  const int wg = (blockIdx.x & 7) * 32 + (blockIdx.x >> 3);  // 256%8==0
  const int kc = wg >> 6;
  const int rem = wg & 63;
  const int brow = (rem >> 2) * 256;
  const int bcol = (rem & 3) * 256;
  const int e = kc >> 1, ih = kc & 1;
  const int lane = tid & 63;
  const int wm = (tid >> 6) >> 2;  // 0..1
  const int wn = (tid >> 6) & 3;   // 0..3
  const int r16 = lane & 15, kh = lane >> 4;

  const ushort_t* aBase = act + ((size_t)e * T_DIM + brow) * I_DIM + ih * 1024;
  const ushort_t* bBase = w2T + ((size_t)e * H_DIM + bcol) * I_DIM + ih * 1024;

  f32x4 acc[8][4];
  const f32x4 zf = {0.f, 0.f, 0.f, 0.f};
#pragma unroll
  for (int m = 0; m < 8; ++m)
#pragma unroll
    for (int n = 0; n < 4; ++n) acc[m][n] = zf;

  auto stageA = [&](int buf, int ksub, int kt) {
#pragma unroll
    for (int j = 0; j < 2; ++j) {
      const int row = j * 128 + (tid >> 2);
      const int col = (tid & 3) * 8;
      gload_lds16(aBase + (size_t)row * I_DIM + kt * 64 + ksub * 32 + col,
                  &lds[buf][ksub * 2][(j * 512 + (tid & ~63)) * 8]);
    }
  };
  auto stageB = [&](int buf, int ksub, int kt) {
#pragma unroll
    for (int j = 0; j < 2; ++j) {
      const int row = j * 128 + (tid >> 2);
      const int col = (tid & 3) * 8;
      gload_lds16(bBase + (size_t)row * I_DIM + kt * 64 + ksub * 32 + col,
                  &lds[buf][ksub * 2 + 1][(j * 512 + (tid & ~63)) * 8]);
    }
  };
  auto rdA = [&](int buf, int ksub, int m) -> bf16x8 {
    const int r = wm * 128 + m * 16 + r16;
    return *(const bf16x8*)&lds[buf][ksub * 2][r * 32 + kh * 8];
  };
  auto rdB = [&](int buf, int ksub, int n) -> bf16x8 {
    const int r = wn * 64 + n * 16 + r16;
    return *(const bf16x8*)&lds[buf][ksub * 2 + 1][r * 32 + kh * 8];
  };

  stageA(0, 0, 0); IRFENCE();
  stageB(0, 0, 0); IRFENCE();
  stageA(0, 1, 0); IRFENCE();
  stageB(0, 1, 0);
  WAITV(4);
  S_BARRIER();

  bf16x8 a[4], b[4];
#pragma unroll 1
  for (int t = 0; t < 15; ++t) {
    const int cur = t & 1, nxt = cur ^ 1;
    // ph0: ksub0, m0-3 (reads u0,u1)
#pragma unroll
    for (int m = 0; m < 4; ++m) a[m] = rdA(cur, 0, m);
#pragma unroll
    for (int n = 0; n < 4; ++n) b[n] = rdB(cur, 0, n);
    stageA(nxt, 0, t + 1);
    S_BARRIER();
    __builtin_amdgcn_s_setprio(1);
#pragma unroll
    for (int m = 0; m < 4; ++m)
#pragma unroll
      for (int n = 0; n < 4; ++n) MFMA16(acc[m][n], a[m], b[n]);
    __builtin_amdgcn_s_setprio(0);
    WAITV(6);
    S_BARRIER();
    __builtin_amdgcn_sched_barrier(0);
    // ph1: ksub0, m4-7 (reads u0; reuses b)
#pragma unroll
    for (int m = 0; m < 4; ++m) a[m] = rdA(cur, 0, m + 4);
    stageB(nxt, 0, t + 1);
    S_BARRIER();
    __builtin_amdgcn_s_setprio(1);
#pragma unroll
    for (int m = 0; m < 4; ++m)
#pragma unroll
      for (int n = 0; n < 4; ++n) MFMA16(acc[m + 4][n], a[m], b[n]);
    __builtin_amdgcn_s_setprio(0);
    WAITV(4);
    S_BARRIER();
    __builtin_amdgcn_sched_barrier(0);
    // ph2: ksub1, m0-3 (reads u2,u3)
#pragma unroll
    for (int m = 0; m < 4; ++m) a[m] = rdA(cur, 1, m);
#pragma unroll
    for (int n = 0; n < 4; ++n) b[n] = rdB(cur, 1, n);
    stageA(nxt, 1, t + 1);
    S_BARRIER();
    __builtin_amdgcn_s_setprio(1);
#pragma unroll
    for (int m = 0; m < 4; ++m)
#pragma unroll
      for (int n = 0; n < 4; ++n) MFMA16(acc[m][n], a[m], b[n]);
    __builtin_amdgcn_s_setprio(0);
    WAITV(6);
    S_BARRIER();
    __builtin_amdgcn_sched_barrier(0);
    // ph3: ksub1, m4-7
#pragma unroll
    for (int m = 0; m < 4; ++m) a[m] = rdA(cur, 1, m + 4);
    stageB(nxt, 1, t + 1);
    S_BARRIER();
    __builtin_amdgcn_s_setprio(1);
#pragma unroll
    for (int m = 0; m < 4; ++m)
#pragma unroll
      for (int n = 0; n < 4; ++n) MFMA16(acc[m + 4][n], a[m], b[n]);
    __builtin_amdgcn_s_setprio(0);
    WAITV(4);
    S_BARRIER();
    __builtin_amdgcn_sched_barrier(0);
  }
  // Tail tile t=15 (buf 1)
  {
#pragma unroll
    for (int m = 0; m < 4; ++m) a[m] = rdA(1, 0, m);
#pragma unroll
    for (int n = 0; n < 4; ++n) b[n] = rdB(1, 0, n);
#pragma unroll
    for (int m = 0; m < 4; ++m)
#pragma unroll
      for (int n = 0; n < 4; ++n) MFMA16(acc[m][n], a[m], b[n]);
#pragma unroll
    for (int m = 0; m < 4; ++m) a[m] = rdA(1, 0, m + 4);
#pragma unroll
    for (int m = 0; m < 4; ++m)
#pragma unroll
      for (int n = 0; n < 4; ++n) MFMA16(acc[m + 4][n], a[m], b[n]);
    WAITV(0);
    S_BARRIER();
#pragma unroll
    for (int m = 0; m < 4; ++m) a[m] = rdA(1, 1, m);
#pragma unroll
    for (int n = 0; n < 4; ++n) b[n] = rdB(1, 1, n);
#pragma unroll
    for (int m = 0; m < 4; ++m)
#pragma unroll
      for (int n = 0; n < 4; ++n) MFMA16(acc[m][n], a[m], b[n]);
#pragma unroll
    for (int m = 0; m < 4; ++m) a[m] = rdA(1, 1, m + 4);
#pragma unroll
    for (int m = 0; m < 4; ++m)
#pragma unroll
      for (int n = 0; n < 4; ++n) MFMA16(acc[m + 4][n], a[m], b[n]);
  }

  // Epilogue: atomic accumulate 0.5*acc into out (pre-initialized with x + bias).
#pragma unroll
  for (int m = 0; m < 8; ++m)
#pragma unroll
    for (int n = 0; n < 4; ++n) {
      const int gcol = bcol + wn * 64 + n * 16 + r16;
#pragma unroll
      for (int rr = 0; rr < 4; ++rr) {
        const int grow = brow + wm * 128 + m * 16 + kh * 4 + rr;
        atomicAdd(&out[(size_t)grow * H_DIM + gcol], 0.5f * acc[m][n][rr]);
      }
    }
}

extern "C" void kernel_launch(void* const* d_in, const int* in_sizes, int n_in,
                              void* d_out, int out_size, void* d_ws, size_t ws_size,
                              hipStream_t stream) {
  const float* x = (const float*)d_in[0];
  const float* scale = (const float*)d_in[1];
  // d_in[2]=gate_kernel, d_in[3]=gate_bias: static routing, logits unused.
  const float* w1 = (const float*)d_in[4];
  const float* b1 = (const float*)d_in[5];
  const float* w2 = (const float*)d_in[6];
  const float* b2 = (const float*)d_in[7];
  float* out = (float*)d_out;

  ushort_t* ws = (ushort_t*)d_ws;
  ushort_t* normed = ws;                                    // [T][H]
  ushort_t* w1T = normed + (size_t)T_DIM * H_DIM;           // [2][2I][H]
  ushort_t* w2T = w1T + (size_t)2 * 2 * I_DIM * H_DIM;      // [2][H][I]
  ushort_t* actb = w2T + (size_t)2 * H_DIM * I_DIM;         // [2][T][I]

  k_rmsnorm<<<dim3(T_DIM), 256, 0, stream>>>(x, scale, normed);
  k_transpose_cvt<<<dim3(2 * I_DIM / 32, H_DIM / 32, 2), 256, 0, stream>>>(
      w1, w1T, H_DIM, 2 * I_DIM);
  k_transpose_cvt<<<dim3(H_DIM / 32, I_DIM / 32, 2), 256, 0, stream>>>(
      w2, w2T, I_DIM, H_DIM);
  k_init_out<<<dim3(T_DIM * H_DIM / 4 / 256), 256, 0, stream>>>(x, b2, out);
  k_gemm1_8ph<<<dim3(512), 512, 0, stream>>>(normed, w1T, b1, actb);
  k_gemm2_8ph<<<dim3(256), 512, 0, stream>>>(actb, w2T, out);
}

// Round 4
// 155.624 us; speedup vs baseline: 1.1467x; 1.1467x over previous
//
#include <hip/hip_runtime.h>
#include <hip/hip_bf16.h>
#include <stdint.h>

#define T_DIM 4096
#define H_DIM 1024
#define I_DIM 2048

typedef __bf16 bf16x8 __attribute__((ext_vector_type(8)));
typedef float f32x4 __attribute__((ext_vector_type(4)));
typedef unsigned short ushort_t;
typedef unsigned short us4 __attribute__((ext_vector_type(4)));

__device__ __forceinline__ unsigned short f32_to_bf16(float f) {
  unsigned int u = __float_as_uint(f);
  u += 0x7fffu + ((u >> 16) & 1u);  // RNE
  return (unsigned short)(u >> 16);
}

__device__ __forceinline__ void gload_lds16(const void* g, void* l) {
  __builtin_amdgcn_global_load_lds(
      (__attribute__((address_space(1))) void*)(uintptr_t)g,
      (__attribute__((address_space(3))) void*)(unsigned int)(uintptr_t)l,
      16, 0, 0);
}

// XOR swizzle on byte offsets within a unit. Involution (key bits 7-9 are
// not modified). Spreads the 16 rows a 16-lane quarter reads across all 8
// 16B-slots of the 128B bank period -> 2 lanes/slot = conflict-free (m136).
__device__ __forceinline__ int swz(int L) { return L ^ (((L >> 7) & 7) << 4); }

#define S_BARRIER() asm volatile("s_barrier" ::: "memory")
#define WAITV(n) asm volatile("s_waitcnt vmcnt(" #n ")" ::: "memory")
#define IRFENCE() asm volatile("" ::: "memory")
#define MFMA16(acc, va, vb) \
  acc = __builtin_amdgcn_mfma_f32_16x16x32_bf16(va, vb, acc, 0, 0, 0)

// ---------------- rmsnorm: x[T][H] f32 -> normed bf16 ----------------
__global__ __launch_bounds__(256) void k_rmsnorm(const float* __restrict__ x,
                                                 const float* __restrict__ scale,
                                                 ushort_t* __restrict__ normed) {
  const int row = blockIdx.x, tid = threadIdx.x;
  const float4 v = ((const float4*)(x + (size_t)row * H_DIM))[tid];
  float ss = v.x * v.x + v.y * v.y + v.z * v.z + v.w * v.w;
#pragma unroll
  for (int off = 32; off > 0; off >>= 1) ss += __shfl_xor(ss, off);
  __shared__ float wsum[4];
  if ((tid & 63) == 0) wsum[tid >> 6] = ss;
  __syncthreads();
  const float tot = wsum[0] + wsum[1] + wsum[2] + wsum[3];
  const float inv = rsqrtf(tot * (1.0f / H_DIM) + 1e-5f);
  const float4 sc = ((const float4*)scale)[tid];
  us4 o;
  o.x = f32_to_bf16(v.x * inv * sc.x);
  o.y = f32_to_bf16(v.y * inv * sc.y);
  o.z = f32_to_bf16(v.z * inv * sc.z);
  o.w = f32_to_bf16(v.w * inv * sc.w);
  ((us4*)(normed + (size_t)row * H_DIM))[tid] = o;
}

// ------- transpose+convert: src[R][C] f32 -> dst[C][R] bf16 (per blockIdx.z) -------
__global__ __launch_bounds__(256) void k_transpose_cvt(const float* __restrict__ src,
                                                       ushort_t* __restrict__ dst,
                                                       int R, int C) {
  __shared__ float tile[32][33];
  const size_t eoff = (size_t)blockIdx.z * (size_t)R * (size_t)C;
  src += eoff;
  dst += eoff;
  const int x0 = blockIdx.x * 32, y0 = blockIdx.y * 32;
  const int tx = threadIdx.x & 31, ty = threadIdx.x >> 5;
#pragma unroll
  for (int i = 0; i < 4; ++i)
    tile[ty + 8 * i][tx] = src[(size_t)(y0 + ty + 8 * i) * C + x0 + tx];
  __syncthreads();
#pragma unroll
  for (int i = 0; i < 4; ++i)
    dst[(size_t)(x0 + ty + 8 * i) * R + y0 + tx] = f32_to_bf16(tile[tx][ty + 8 * i]);
}

// ---------------- out init: out = x + 0.5*(b2[0]+b2[1]) ----------------
__global__ __launch_bounds__(256) void k_init_out(const float* __restrict__ x,
                                                  const float* __restrict__ b2,
                                                  float* __restrict__ out) {
  const int idx = blockIdx.x * 256 + threadIdx.x;  // over T*H/4
  const int col4 = idx & (H_DIM / 4 - 1);
  const float4 xv = ((const float4*)x)[idx];
  const float4 b0 = ((const float4*)b2)[col4];
  const float4 b1 = ((const float4*)(b2 + H_DIM))[col4];
  float4 o;
  o.x = xv.x + 0.5f * (b0.x + b1.x);
  o.y = xv.y + 0.5f * (b0.y + b1.y);
  o.z = xv.z + 0.5f * (b0.z + b1.z);
  o.w = xv.w + 0.5f * (b0.w + b1.w);
  ((float4*)out)[idx] = o;
}

// ---------------- GEMM1 8-phase + T2 swizzle ----------------
// Tile: 256 rows x 128 cols (gate AND linear share A). BK=64 as 2 k-half units.
// Units per dbuf: u0=A_k0[256][32](16KB), u1={Bg_k0[128][32],Bl_k0[128][32]}(16KB),
// u2=A_k1, u3=B_k1. LDS linear for global_load_lds; swizzle via pre-swizzled
// global source + swizzled ds_read offsets (rule 21).
__global__ __launch_bounds__(512, 2) void k_gemm1_8ph(
    const ushort_t* __restrict__ normed, const ushort_t* __restrict__ w1T,
    const float* __restrict__ b1, ushort_t* __restrict__ act) {
  __shared__ __align__(16) ushort_t lds[2][4][8192];  // 128 KiB
  const int tid = threadIdx.x;
  const int wg = (blockIdx.x & 7) * 64 + (blockIdx.x >> 3);  // XCD swizzle (512%8==0)
  const int e = wg >> 8;
  const int rem = wg & 255;
  const int brow = (rem >> 4) * 256;
  const int bcol = (rem & 15) * 128;
  const int lane = tid & 63;
  const int wm = (tid >> 6) >> 1;  // 0..3
  const int wn = (tid >> 6) & 1;   // 0..1
  const int r16 = lane & 15, kh = lane >> 4;

  const ushort_t* aBase = normed + (size_t)brow * H_DIM;
  const ushort_t* gBase = w1T + ((size_t)e * 2 * I_DIM + bcol) * H_DIM;
  const ushort_t* lBase = gBase + (size_t)I_DIM * H_DIM;

  f32x4 accg[4][4], accl[4][4];
  const f32x4 zf = {0.f, 0.f, 0.f, 0.f};
#pragma unroll
  for (int m = 0; m < 4; ++m)
#pragma unroll
    for (int n = 0; n < 4; ++n) { accg[m][n] = zf; accl[m][n] = zf; }

  // Pre-swizzled per-thread source decomposition for staging (2 chunks/unit).
  int srow[2], scolb[2];
#pragma unroll
  for (int j = 0; j < 2; ++j) {
    const int u = swz((j * 512 + tid) * 16);
    srow[j] = u >> 6;           // 0..255
    scolb[j] = (u & 63) >> 1;   // element offset within 32-elem k-slice
  }
  const int ldst0 = (tid & ~63) * 16;          // byte, + j*8192

  auto stageA = [&](int buf, int ksub, int kt) {
    const int kc = kt * 64 + ksub * 32;
#pragma unroll
    for (int j = 0; j < 2; ++j)
      gload_lds16(aBase + (size_t)srow[j] * H_DIM + kc + scolb[j],
                  (char*)&lds[buf][ksub * 2][0] + j * 8192 + ldst0);
  };
  auto stageB = [&](int buf, int ksub, int kt) {
    const int kc = kt * 64 + ksub * 32;
    gload_lds16(gBase + (size_t)srow[0] * H_DIM + kc + scolb[0],
                (char*)&lds[buf][ksub * 2 + 1][0] + ldst0);
    gload_lds16(lBase + (size_t)(srow[1] - 128) * H_DIM + kc + scolb[1],
                (char*)&lds[buf][ksub * 2 + 1][0] + 8192 + ldst0);
  };

  // Precomputed swizzled fragment byte-offsets (loop-invariant).
  int aoffs[4], boffs[4];
#pragma unroll
  for (int m = 0; m < 4; ++m)
    aoffs[m] = swz((wm * 64 + m * 16 + r16) * 64 + kh * 16);
#pragma unroll
  for (int n = 0; n < 4; ++n)
    boffs[n] = swz((wn * 64 + n * 16 + r16) * 64 + kh * 16);

  auto rdA = [&](int buf, int ksub, int m) -> bf16x8 {
    return *(const bf16x8*)((const char*)&lds[buf][ksub * 2][0] + aoffs[m]);
  };
  auto rdBg = [&](int buf, int ksub, int n) -> bf16x8 {
    return *(const bf16x8*)((const char*)&lds[buf][ksub * 2 + 1][0] + boffs[n]);
  };
  auto rdBl = [&](int buf, int ksub, int n) -> bf16x8 {
    return *(const bf16x8*)((const char*)&lds[buf][ksub * 2 + 1][0] + 8192 + boffs[n]);
  };

  // Prologue: tile 0, units u0,u1,u2,u3 (2 loads each).
  stageA(0, 0, 0); IRFENCE();
  stageB(0, 0, 0); IRFENCE();
  stageA(0, 1, 0); IRFENCE();
  stageB(0, 1, 0);
  WAITV(4);  // u0,u1 landed
  S_BARRIER();

  bf16x8 a[4], b[4];
#pragma unroll 1
  for (int t = 0; t < 15; ++t) {
    const int cur = t & 1, nxt = cur ^ 1;
    // ph0: gate ks0 (reads u0,u1; stages u0')
#pragma unroll
    for (int m = 0; m < 4; ++m) a[m] = rdA(cur, 0, m);
#pragma unroll
    for (int n = 0; n < 4; ++n) b[n] = rdBg(cur, 0, n);
    stageA(nxt, 0, t + 1);
    S_BARRIER();
    __builtin_amdgcn_s_setprio(1);
#pragma unroll
    for (int m = 0; m < 4; ++m)
#pragma unroll
      for (int n = 0; n < 4; ++n) MFMA16(accg[m][n], a[m], b[n]);
    __builtin_amdgcn_s_setprio(0);
    WAITV(6);
    S_BARRIER();
    __builtin_amdgcn_sched_barrier(0);
    // ph1: linear ks0 (reads u1; reuses a; stages u1')
#pragma unroll
    for (int n = 0; n < 4; ++n) b[n] = rdBl(cur, 0, n);
    stageB(nxt, 0, t + 1);
    S_BARRIER();
    __builtin_amdgcn_s_setprio(1);
#pragma unroll
    for (int m = 0; m < 4; ++m)
#pragma unroll
      for (int n = 0; n < 4; ++n) MFMA16(accl[m][n], a[m], b[n]);
    __builtin_amdgcn_s_setprio(0);
    WAITV(4);  // drains u2,u3 of cur
    S_BARRIER();
    __builtin_amdgcn_sched_barrier(0);
    // ph2: gate ks1 (reads u2,u3; stages u2')
#pragma unroll
    for (int m = 0; m < 4; ++m) a[m] = rdA(cur, 1, m);
#pragma unroll
    for (int n = 0; n < 4; ++n) b[n] = rdBg(cur, 1, n);
    stageA(nxt, 1, t + 1);
    S_BARRIER();
    __builtin_amdgcn_s_setprio(1);
#pragma unroll
    for (int m = 0; m < 4; ++m)
#pragma unroll
      for (int n = 0; n < 4; ++n) MFMA16(accg[m][n], a[m], b[n]);
    __builtin_amdgcn_s_setprio(0);
    WAITV(6);
    S_BARRIER();
    __builtin_amdgcn_sched_barrier(0);
    // ph3: linear ks1 (reads u3; stages u3')
#pragma unroll
    for (int n = 0; n < 4; ++n) b[n] = rdBl(cur, 1, n);
    stageB(nxt, 1, t + 1);
    S_BARRIER();
    __builtin_amdgcn_s_setprio(1);
#pragma unroll
    for (int m = 0; m < 4; ++m)
#pragma unroll
      for (int n = 0; n < 4; ++n) MFMA16(accl[m][n], a[m], b[n]);
    __builtin_amdgcn_s_setprio(0);
    WAITV(4);  // drains u0',u1' -> next iter reads them
    S_BARRIER();
    __builtin_amdgcn_sched_barrier(0);
  }
  // Tail tile t=15 (buf 1; u0,u1 landed, u2,u3 still in flight).
  {
#pragma unroll
    for (int m = 0; m < 4; ++m) a[m] = rdA(1, 0, m);
#pragma unroll
    for (int n = 0; n < 4; ++n) b[n] = rdBg(1, 0, n);
#pragma unroll
    for (int m = 0; m < 4; ++m)
#pragma unroll
      for (int n = 0; n < 4; ++n) MFMA16(accg[m][n], a[m], b[n]);
#pragma unroll
    for (int n = 0; n < 4; ++n) b[n] = rdBl(1, 0, n);
#pragma unroll
    for (int m = 0; m < 4; ++m)
#pragma unroll
      for (int n = 0; n < 4; ++n) MFMA16(accl[m][n], a[m], b[n]);
    WAITV(0);
    S_BARRIER();  // ALL waves' staging of u2,u3 drained (fix: was missing in R3)
#pragma unroll
    for (int m = 0; m < 4; ++m) a[m] = rdA(1, 1, m);
#pragma unroll
    for (int n = 0; n < 4; ++n) b[n] = rdBg(1, 1, n);
#pragma unroll
    for (int m = 0; m < 4; ++m)
#pragma unroll
      for (int n = 0; n < 4; ++n) MFMA16(accg[m][n], a[m], b[n]);
#pragma unroll
    for (int n = 0; n < 4; ++n) b[n] = rdBl(1, 1, n);
#pragma unroll
    for (int m = 0; m < 4; ++m)
#pragma unroll
      for (int n = 0; n < 4; ++n) MFMA16(accl[m][n], a[m], b[n]);
  }

  // Epilogue: bias + clip + sigmoid-gate, store bf16 act.
  const float* b1e = b1 + (size_t)e * 2 * I_DIM;
#pragma unroll
  for (int m = 0; m < 4; ++m)
#pragma unroll
    for (int n = 0; n < 4; ++n) {
      const int gcol = bcol + wn * 64 + n * 16 + r16;
      const float bgb = b1e[gcol];
      const float blb = b1e[I_DIM + gcol];
#pragma unroll
      for (int rr = 0; rr < 4; ++rr) {
        const int grow = brow + wm * 64 + m * 16 + kh * 4 + rr;
        const float hg = accg[m][n][rr] + bgb;
        const float hl = accl[m][n][rr] + blb;
        const float g = fminf(hg, 7.f);
        const float l = fminf(fmaxf(hl, -7.f), 7.f);
        const float s = 1.f / (1.f + __expf(-1.702f * g));
        const float av = g * s * (l + 1.f);
        act[((size_t)e * T_DIM + grow) * I_DIM + gcol] = f32_to_bf16(av);
      }
    }
}

// ---------------- GEMM2: 256x128 tile, split-K=2 (by expert), swizzled 8-wave ----
// Units per dbuf: u0=A_k0[256][32](16KB), u1=B_k0[128][32](8KB), u2=A_k1, u3=B_k1.
// 96 KiB LDS. 2 phases/K-tile, counted vmcnt(3). Epilogue: atomicAdd 0.5*acc.
__global__ __launch_bounds__(512, 2) void k_gemm2_8ph(
    const ushort_t* __restrict__ act, const ushort_t* __restrict__ w2T,
    float* __restrict__ out) {
  __shared__ __align__(16) ushort_t lds[2][2][12288];  // [buf][ksub]{A:16KB,B:8KB}
  const int tid = threadIdx.x;
  const int wg = (blockIdx.x & 7) * 32 + (blockIdx.x >> 3);  // 256%8==0
  const int e = wg >> 7;
  const int tileid = wg & 127;
  const int brow = (tileid >> 3) * 256;  // 16
  const int bcol = (tileid & 7) * 128;   // 8
  const int lane = tid & 63;
  const int wm = (tid >> 6) >> 1;  // 0..3
  const int wn = (tid >> 6) & 1;   // 0..1
  const int r16 = lane & 15, kh = lane >> 4;

  const ushort_t* aBase = act + ((size_t)e * T_DIM + brow) * I_DIM;
  const ushort_t* bBase = w2T + ((size_t)e * H_DIM + bcol) * I_DIM;

  f32x4 acc[4][4];
  const f32x4 zf = {0.f, 0.f, 0.f, 0.f};
#pragma unroll
  for (int m = 0; m < 4; ++m)
#pragma unroll
    for (int n = 0; n < 4; ++n) acc[m][n] = zf;

  int srow[2], scolb[2];
#pragma unroll
  for (int j = 0; j < 2; ++j) {
    const int u = swz((j * 512 + tid) * 16);
    srow[j] = u >> 6;
    scolb[j] = (u & 63) >> 1;
  }
  const int ldst0 = (tid & ~63) * 16;

  auto stageA = [&](int buf, int ksub, int kt) {
    const int kc = kt * 64 + ksub * 32;
#pragma unroll
    for (int j = 0; j < 2; ++j)
      gload_lds16(aBase + (size_t)srow[j] * I_DIM + kc + scolb[j],
                  (char*)&lds[buf][ksub][0] + j * 8192 + ldst0);
  };
  auto stageB = [&](int buf, int ksub, int kt) {
    const int kc = kt * 64 + ksub * 32;
    gload_lds16(bBase + (size_t)srow[0] * I_DIM + kc + scolb[0],
                (char*)&lds[buf][ksub][0] + 16384 + ldst0);
  };

  int aoffs[4], boffs[4];
#pragma unroll
  for (int m = 0; m < 4; ++m)
    aoffs[m] = swz((wm * 64 + m * 16 + r16) * 64 + kh * 16);
#pragma unroll
  for (int n = 0; n < 4; ++n)
    boffs[n] = swz((wn * 64 + n * 16 + r16) * 64 + kh * 16);

  auto rdA = [&](int buf, int ksub, int m) -> bf16x8 {
    return *(const bf16x8*)((const char*)&lds[buf][ksub][0] + aoffs[m]);
  };
  auto rdB = [&](int buf, int ksub, int n) -> bf16x8 {
    return *(const bf16x8*)((const char*)&lds[buf][ksub][0] + 16384 + boffs[n]);
  };

  // Prologue: u0(2), u1(1), u2(2), u3(1) = 6 outstanding.
  stageA(0, 0, 0); IRFENCE();
  stageB(0, 0, 0); IRFENCE();
  stageA(0, 1, 0); IRFENCE();
  stageB(0, 1, 0);
  WAITV(3);  // u0,u1 landed
  S_BARRIER();

  bf16x8 a[4], b[4];
#pragma unroll 1
  for (int t = 0; t < 31; ++t) {
    const int cur = t & 1, nxt = cur ^ 1;
    // ph0: ks0 (reads u0,u1; stages u0',u1' = 3 insts)
#pragma unroll
    for (int m = 0; m < 4; ++m) a[m] = rdA(cur, 0, m);
#pragma unroll
    for (int n = 0; n < 4; ++n) b[n] = rdB(cur, 0, n);
    stageA(nxt, 0, t + 1);
    stageB(nxt, 0, t + 1);
    S_BARRIER();
    __builtin_amdgcn_s_setprio(1);
#pragma unroll
    for (int m = 0; m < 4; ++m)
#pragma unroll
      for (int n = 0; n < 4; ++n) MFMA16(acc[m][n], a[m], b[n]);
    __builtin_amdgcn_s_setprio(0);
    WAITV(3);  // drains u2,u3 of cur
    S_BARRIER();
    __builtin_amdgcn_sched_barrier(0);
    // ph1: ks1 (reads u2,u3; stages u2',u3')
#pragma unroll
    for (int m = 0; m < 4; ++m) a[m] = rdA(cur, 1, m);
#pragma unroll
    for (int n = 0; n < 4; ++n) b[n] = rdB(cur, 1, n);
    stageA(nxt, 1, t + 1);
    stageB(nxt, 1, t + 1);
    S_BARRIER();
    __builtin_amdgcn_s_setprio(1);
#pragma unroll
    for (int m = 0; m < 4; ++m)
#pragma unroll
      for (int n = 0; n < 4; ++n) MFMA16(acc[m][n], a[m], b[n]);
    __builtin_amdgcn_s_setprio(0);
    WAITV(3);  // drains u0',u1'
    S_BARRIER();
    __builtin_amdgcn_sched_barrier(0);
  }
  // Tail tile t=31 (buf 1; u0,u1 landed, u2,u3 in flight).
  {
#pragma unroll
    for (int m = 0; m < 4; ++m) a[m] = rdA(1, 0, m);
#pragma unroll
    for (int n = 0; n < 4; ++n) b[n] = rdB(1, 0, n);
#pragma unroll
    for (int m = 0; m < 4; ++m)
#pragma unroll
      for (int n = 0; n < 4; ++n) MFMA16(acc[m][n], a[m], b[n]);
    WAITV(0);
    S_BARRIER();  // ALL waves' staging of u2,u3 drained (fix: was missing in R3)
#pragma unroll
    for (int m = 0; m < 4; ++m) a[m] = rdA(1, 1, m);
#pragma unroll
    for (int n = 0; n < 4; ++n) b[n] = rdB(1, 1, n);
#pragma unroll
    for (int m = 0; m < 4; ++m)
#pragma unroll
      for (int n = 0; n < 4; ++n) MFMA16(acc[m][n], a[m], b[n]);
  }

  // Epilogue: atomic accumulate 0.5*acc into out (pre-initialized x + bias).
#pragma unroll
  for (int m = 0; m < 4; ++m)
#pragma unroll
    for (int n = 0; n < 4; ++n) {
      const int gcol = bcol + wn * 64 + n * 16 + r16;
#pragma unroll
      for (int rr = 0; rr < 4; ++rr) {
        const int grow = brow + wm * 64 + m * 16 + kh * 4 + rr;
        atomicAdd(&out[(size_t)grow * H_DIM + gcol], 0.5f * acc[m][n][rr]);
      }
    }
}

extern "C" void kernel_launch(void* const* d_in, const int* in_sizes, int n_in,
                              void* d_out, int out_size, void* d_ws, size_t ws_size,
                              hipStream_t stream) {
  const float* x = (const float*)d_in[0];
  const float* scale = (const float*)d_in[1];
  // d_in[2]=gate_kernel, d_in[3]=gate_bias: static routing, logits unused.
  const float* w1 = (const float*)d_in[4];
  const float* b1 = (const float*)d_in[5];
  const float* w2 = (const float*)d_in[6];
  const float* b2 = (const float*)d_in[7];
  float* out = (float*)d_out;

  ushort_t* ws = (ushort_t*)d_ws;
  ushort_t* normed = ws;                                    // [T][H]
  ushort_t* w1T = normed + (size_t)T_DIM * H_DIM;           // [2][2I][H]
  ushort_t* w2T = w1T + (size_t)2 * 2 * I_DIM * H_DIM;      // [2][H][I]
  ushort_t* actb = w2T + (size_t)2 * H_DIM * I_DIM;         // [2][T][I]

  k_rmsnorm<<<dim3(T_DIM), 256, 0, stream>>>(x, scale, normed);
  k_transpose_cvt<<<dim3(2 * I_DIM / 32, H_DIM / 32, 2), 256, 0, stream>>>(
      w1, w1T, H_DIM, 2 * I_DIM);
  k_transpose_cvt<<<dim3(H_DIM / 32, I_DIM / 32, 2), 256, 0, stream>>>(
      w2, w2T, I_DIM, H_DIM);
  k_init_out<<<dim3(T_DIM * H_DIM / 4 / 256), 256, 0, stream>>>(x, b2, out);
  k_gemm1_8ph<<<dim3(512), 512, 0, stream>>>(normed, w1T, b1, actb);
  k_gemm2_8ph<<<dim3(256), 512, 0, stream>>>(actb, w2T, out);
}

// Round 5
// 149.872 us; speedup vs baseline: 1.1907x; 1.0384x over previous
//
#include <hip/hip_runtime.h>
#include <hip/hip_bf16.h>
#include <stdint.h>

#define T_DIM 4096
#define H_DIM 1024
#define I_DIM 2048

typedef __bf16 bf16x8 __attribute__((ext_vector_type(8)));
typedef float f32x4 __attribute__((ext_vector_type(4)));
typedef unsigned short ushort_t;
typedef unsigned short us4 __attribute__((ext_vector_type(4)));

__device__ __forceinline__ unsigned short f32_to_bf16(float f) {
  unsigned int u = __float_as_uint(f);
  u += 0x7fffu + ((u >> 16) & 1u);  // RNE
  return (unsigned short)(u >> 16);
}

__device__ __forceinline__ void gload_lds16(const void* g, void* l) {
  __builtin_amdgcn_global_load_lds(
      (__attribute__((address_space(1))) void*)(uintptr_t)g,
      (__attribute__((address_space(3))) void*)(unsigned int)(uintptr_t)l,
      16, 0, 0);
}

// XOR swizzle on byte offsets within a 16KB unit (involution; key bits 7-9
// untouched). ds_read_b128 fragment reads: 2 lanes/16B-slot = conflict-free
// (verified R4: SQ_LDS_BANK_CONFLICT = 0).
__device__ __forceinline__ int swz(int L) { return L ^ (((L >> 7) & 7) << 4); }

#define S_BARRIER() asm volatile("s_barrier" ::: "memory")
#define WAITV(n) asm volatile("s_waitcnt vmcnt(" #n ")" ::: "memory")
#define IRFENCE() asm volatile("" ::: "memory")
#define MFMA16(acc, va, vb) \
  acc = __builtin_amdgcn_mfma_f32_16x16x32_bf16(va, vb, acc, 0, 0, 0)

// ------- rmsnorm + out-init fused: normed = rms(x)*scale (bf16);
//         out = x + 0.5*(b2[0]+b2[1])  (gemm2 atomically accumulates later) ---
__global__ __launch_bounds__(256) void k_rmsnorm_init(
    const float* __restrict__ x, const float* __restrict__ scale,
    const float* __restrict__ b2, ushort_t* __restrict__ normed,
    float* __restrict__ out) {
  const int row = blockIdx.x, tid = threadIdx.x;
  const float4 v = ((const float4*)(x + (size_t)row * H_DIM))[tid];
  float ss = v.x * v.x + v.y * v.y + v.z * v.z + v.w * v.w;
#pragma unroll
  for (int off = 32; off > 0; off >>= 1) ss += __shfl_xor(ss, off);
  __shared__ float wsum[4];
  if ((tid & 63) == 0) wsum[tid >> 6] = ss;
  __syncthreads();
  const float tot = wsum[0] + wsum[1] + wsum[2] + wsum[3];
  const float inv = rsqrtf(tot * (1.0f / H_DIM) + 1e-5f);
  const float4 sc = ((const float4*)scale)[tid];
  us4 o;
  o.x = f32_to_bf16(v.x * inv * sc.x);
  o.y = f32_to_bf16(v.y * inv * sc.y);
  o.z = f32_to_bf16(v.z * inv * sc.z);
  o.w = f32_to_bf16(v.w * inv * sc.w);
  ((us4*)(normed + (size_t)row * H_DIM))[tid] = o;
  const float4 b0 = ((const float4*)b2)[tid];
  const float4 b1 = ((const float4*)(b2 + H_DIM))[tid];
  float4 ov;
  ov.x = v.x + 0.5f * (b0.x + b1.x);
  ov.y = v.y + 0.5f * (b0.y + b1.y);
  ov.z = v.z + 0.5f * (b0.z + b1.z);
  ov.w = v.w + 0.5f * (b0.w + b1.w);
  ((float4*)(out + (size_t)row * H_DIM))[tid] = ov;
}

// ------- transpose+convert: src[R][C] f32 -> dst[C][R] bf16 (per blockIdx.z) ---
__global__ __launch_bounds__(256) void k_transpose_cvt(const float* __restrict__ src,
                                                       ushort_t* __restrict__ dst,
                                                       int R, int C) {
  __shared__ float tile[32][33];
  const size_t eoff = (size_t)blockIdx.z * (size_t)R * (size_t)C;
  src += eoff;
  dst += eoff;
  const int x0 = blockIdx.x * 32, y0 = blockIdx.y * 32;
  const int tx = threadIdx.x & 31, ty = threadIdx.x >> 5;
#pragma unroll
  for (int i = 0; i < 4; ++i)
    tile[ty + 8 * i][tx] = src[(size_t)(y0 + ty + 8 * i) * C + x0 + tx];
  __syncthreads();
#pragma unroll
  for (int i = 0; i < 4; ++i)
    dst[(size_t)(x0 + ty + 8 * i) * R + y0 + tx] = f32_to_bf16(tile[tx][ty + 8 * i]);
}

// ---------------- GEMM1: 256x(128 gate + 128 linear), BK=64, 8 waves ----------
// LDS units (16KB each): [buf][ksub*2]=A(256x32), [buf][ksub*2+1]={Bg,Bl}(128x32 each).
// Parity-unrolled K-loop: buf indices are compile-time; staging via running
// per-thread pointers. Sync schedule identical to R4 (verified) minus no-op waits.
__global__ __launch_bounds__(512, 2) void k_gemm1_8ph(
    const ushort_t* __restrict__ normed, const ushort_t* __restrict__ w1T,
    const float* __restrict__ b1, ushort_t* __restrict__ act) {
  __shared__ __align__(16) ushort_t lds[2][4][8192];  // 128 KiB
  char* const ldsB = (char*)&lds[0][0][0];
  const int tid = threadIdx.x;
  const int wg = (blockIdx.x & 7) * 64 + (blockIdx.x >> 3);  // XCD swizzle
  const int e = wg >> 8;
  const int rem = wg & 255;
  const int brow = (rem >> 4) * 256;
  const int bcol = (rem & 15) * 128;
  const int lane = tid & 63;
  const int wm = (tid >> 6) >> 1;
  const int wn = (tid >> 6) & 1;
  const int r16 = lane & 15, kh = lane >> 4;

  const ushort_t* aBase = normed + (size_t)brow * H_DIM;
  const ushort_t* gBase = w1T + ((size_t)e * 2 * I_DIM + bcol) * H_DIM;
  const ushort_t* lBase = gBase + (size_t)I_DIM * H_DIM;

  f32x4 accg[4][4], accl[4][4];
  const f32x4 zf = {0.f, 0.f, 0.f, 0.f};
#pragma unroll
  for (int m = 0; m < 4; ++m)
#pragma unroll
    for (int n = 0; n < 4; ++n) { accg[m][n] = zf; accl[m][n] = zf; }

  // Pre-swizzled staging decomposition (rule 21: linear LDS dest, swizzled src).
  int srow[2], scolb[2];
#pragma unroll
  for (int j = 0; j < 2; ++j) {
    const int u = swz((j * 512 + tid) * 16);
    srow[j] = u >> 6;
    scolb[j] = (u & 63) >> 1;
  }
  const int ldst0 = (tid & ~63) * 16;  // bytes

  // Running stage pointers (point at NEXT K-tile to stage; advance +64/K-tile).
  const ushort_t* pA0 = aBase + (size_t)srow[0] * H_DIM + scolb[0];
  const ushort_t* pA1 = aBase + (size_t)srow[1] * H_DIM + scolb[1];
  const ushort_t* pG = gBase + (size_t)srow[0] * H_DIM + scolb[0];
  const ushort_t* pL = lBase + (size_t)(srow[1] - 128) * H_DIM + scolb[1];

  // LDS byte offsets with buf folded in (imms stay < 65536).
  int aoffV[2][4], boffV[2][4];
#pragma unroll
  for (int bq = 0; bq < 2; ++bq) {
#pragma unroll
    for (int m = 0; m < 4; ++m)
      aoffV[bq][m] = bq * 65536 + swz((wm * 64 + m * 16 + r16) * 64 + kh * 16);
#pragma unroll
    for (int n = 0; n < 4; ++n)
      boffV[bq][n] = bq * 65536 + 16384 + swz((wn * 64 + n * 16 + r16) * 64 + kh * 16);
  }

  auto stageA = [&](int buf, int ksub) {
    gload_lds16(pA0 + ksub * 32, ldsB + buf * 65536 + ksub * 32768 + ldst0);
    gload_lds16(pA1 + ksub * 32, ldsB + buf * 65536 + ksub * 32768 + 8192 + ldst0);
  };
  auto stageB = [&](int buf, int ksub) {
    gload_lds16(pG + ksub * 32, ldsB + buf * 65536 + ksub * 32768 + 16384 + ldst0);
    gload_lds16(pL + ksub * 32, ldsB + buf * 65536 + ksub * 32768 + 16384 + 8192 + ldst0);
  };
  auto rdA = [&](int buf, int ksub, int m) -> bf16x8 {
    return *(const bf16x8*)(ldsB + aoffV[buf][m] + ksub * 32768);
  };
  auto rdBg = [&](int buf, int ksub, int n) -> bf16x8 {
    return *(const bf16x8*)(ldsB + boffV[buf][n] + ksub * 32768);
  };
  auto rdBl = [&](int buf, int ksub, int n) -> bf16x8 {
    return *(const bf16x8*)(ldsB + boffV[buf][n] + ksub * 32768 + 8192);
  };

#define G1_ADV() \
  { pA0 += 64; pA1 += 64; pG += 64; pL += 64; }

#define G1_TILE(CUR, NXT)                                                     \
  {                                                                           \
    _Pragma("unroll") for (int m = 0; m < 4; ++m) a[m] = rdA(CUR, 0, m);      \
    _Pragma("unroll") for (int n = 0; n < 4; ++n) b[n] = rdBg(CUR, 0, n);     \
    stageA(NXT, 0);                                                           \
    S_BARRIER();                                                              \
    __builtin_amdgcn_s_setprio(1);                                            \
    _Pragma("unroll") for (int m = 0; m < 4; ++m)                             \
        _Pragma("unroll") for (int n = 0; n < 4; ++n)                         \
            MFMA16(accg[m][n], a[m], b[n]);                                   \
    __builtin_amdgcn_s_setprio(0);                                            \
    S_BARRIER();                                                              \
    __builtin_amdgcn_sched_barrier(0);                                        \
    _Pragma("unroll") for (int n = 0; n < 4; ++n) b[n] = rdBl(CUR, 0, n);     \
    stageB(NXT, 0);                                                           \
    S_BARRIER();                                                              \
    __builtin_amdgcn_s_setprio(1);                                            \
    _Pragma("unroll") for (int m = 0; m < 4; ++m)                             \
        _Pragma("unroll") for (int n = 0; n < 4; ++n)                         \
            MFMA16(accl[m][n], a[m], b[n]);                                   \
    __builtin_amdgcn_s_setprio(0);                                            \
    WAITV(4); /* drains ks1 units of CUR */                                   \
    S_BARRIER();                                                              \
    __builtin_amdgcn_sched_barrier(0);                                        \
    _Pragma("unroll") for (int m = 0; m < 4; ++m) a[m] = rdA(CUR, 1, m);      \
    _Pragma("unroll") for (int n = 0; n < 4; ++n) b[n] = rdBg(CUR, 1, n);     \
    stageA(NXT, 1);                                                           \
    S_BARRIER();                                                              \
    __builtin_amdgcn_s_setprio(1);                                            \
    _Pragma("unroll") for (int m = 0; m < 4; ++m)                             \
        _Pragma("unroll") for (int n = 0; n < 4; ++n)                         \
            MFMA16(accg[m][n], a[m], b[n]);                                   \
    __builtin_amdgcn_s_setprio(0);                                            \
    S_BARRIER();                                                              \
    __builtin_amdgcn_sched_barrier(0);                                        \
    _Pragma("unroll") for (int n = 0; n < 4; ++n) b[n] = rdBl(CUR, 1, n);     \
    stageB(NXT, 1);                                                           \
    S_BARRIER();                                                              \
    __builtin_amdgcn_s_setprio(1);                                            \
    _Pragma("unroll") for (int m = 0; m < 4; ++m)                             \
        _Pragma("unroll") for (int n = 0; n < 4; ++n)                         \
            MFMA16(accl[m][n], a[m], b[n]);                                   \
    __builtin_amdgcn_s_setprio(0);                                            \
    WAITV(4); /* drains ks0 units of NXT */                                   \
    S_BARRIER();                                                              \
    __builtin_amdgcn_sched_barrier(0);                                        \
    G1_ADV();                                                                 \
  }

  // Prologue: stage tile 0, advance pointers to tile 1.
  stageA(0, 0); IRFENCE();
  stageB(0, 0); IRFENCE();
  stageA(0, 1); IRFENCE();
  stageB(0, 1);
  G1_ADV();
  WAITV(4);
  S_BARRIER();

  bf16x8 a[4], b[4];
#pragma unroll 1
  for (int it = 0; it < 7; ++it) {  // tiles 0..13
    G1_TILE(0, 1);
    G1_TILE(1, 0);
  }
  G1_TILE(0, 1);  // tile 14, stages tile 15 into buf1

  // Tail: tile 15 in buf1 (ks0 landed; ks1 in flight).
  {
#pragma unroll
    for (int m = 0; m < 4; ++m) a[m] = rdA(1, 0, m);
#pragma unroll
    for (int n = 0; n < 4; ++n) b[n] = rdBg(1, 0, n);
#pragma unroll
    for (int m = 0; m < 4; ++m)
#pragma unroll
      for (int n = 0; n < 4; ++n) MFMA16(accg[m][n], a[m], b[n]);
#pragma unroll
    for (int n = 0; n < 4; ++n) b[n] = rdBl(1, 0, n);
#pragma unroll
    for (int m = 0; m < 4; ++m)
#pragma unroll
      for (int n = 0; n < 4; ++n) MFMA16(accl[m][n], a[m], b[n]);
    WAITV(0);
    S_BARRIER();  // all waves' ks1 staging drained
#pragma unroll
    for (int m = 0; m < 4; ++m) a[m] = rdA(1, 1, m);
#pragma unroll
    for (int n = 0; n < 4; ++n) b[n] = rdBg(1, 1, n);
#pragma unroll
    for (int m = 0; m < 4; ++m)
#pragma unroll
      for (int n = 0; n < 4; ++n) MFMA16(accg[m][n], a[m], b[n]);
#pragma unroll
    for (int n = 0; n < 4; ++n) b[n] = rdBl(1, 1, n);
#pragma unroll
    for (int m = 0; m < 4; ++m)
#pragma unroll
      for (int n = 0; n < 4; ++n) MFMA16(accl[m][n], a[m], b[n]);
  }
#undef G1_TILE
#undef G1_ADV

  // Epilogue: bias + clip + sigmoid-gate, store bf16 act.
  const float* b1e = b1 + (size_t)e * 2 * I_DIM;
#pragma unroll
  for (int m = 0; m < 4; ++m)
#pragma unroll
    for (int n = 0; n < 4; ++n) {
      const int gcol = bcol + wn * 64 + n * 16 + r16;
      const float bgb = b1e[gcol];
      const float blb = b1e[I_DIM + gcol];
#pragma unroll
      for (int rr = 0; rr < 4; ++rr) {
        const int grow = brow + wm * 64 + m * 16 + kh * 4 + rr;
        const float hg = accg[m][n][rr] + bgb;
        const float hl = accl[m][n][rr] + blb;
        const float g = fminf(hg, 7.f);
        const float l = fminf(fmaxf(hl, -7.f), 7.f);
        const float s = 1.f / (1.f + __expf(-1.702f * g));
        const float av = g * s * (l + 1.f);
        act[((size_t)e * T_DIM + grow) * I_DIM + gcol] = f32_to_bf16(av);
      }
    }
}

// ---------------- GEMM2: 256x128 tile, split-K=2 (expert), parity-unrolled ----
// Units per dbuf (24KB): A(256x32)=16KB + B(128x32)=8KB at +16384. 96 KiB LDS.
__global__ __launch_bounds__(512, 2) void k_gemm2_8ph(
    const ushort_t* __restrict__ act, const ushort_t* __restrict__ w2T,
    float* __restrict__ out) {
  __shared__ __align__(16) ushort_t lds[2][2][12288];
  char* const ldsB = (char*)&lds[0][0][0];
  const int tid = threadIdx.x;
  const int wg = (blockIdx.x & 7) * 32 + (blockIdx.x >> 3);
  const int e = wg >> 7;
  const int tileid = wg & 127;
  const int brow = (tileid >> 3) * 256;
  const int bcol = (tileid & 7) * 128;
  const int lane = tid & 63;
  const int wm = (tid >> 6) >> 1;
  const int wn = (tid >> 6) & 1;
  const int r16 = lane & 15, kh = lane >> 4;

  const ushort_t* aBase = act + ((size_t)e * T_DIM + brow) * I_DIM;
  const ushort_t* bBase = w2T + ((size_t)e * H_DIM + bcol) * I_DIM;

  f32x4 acc[4][4];
  const f32x4 zf = {0.f, 0.f, 0.f, 0.f};
#pragma unroll
  for (int m = 0; m < 4; ++m)
#pragma unroll
    for (int n = 0; n < 4; ++n) acc[m][n] = zf;

  int srow[2], scolb[2];
#pragma unroll
  for (int j = 0; j < 2; ++j) {
    const int u = swz((j * 512 + tid) * 16);
    srow[j] = u >> 6;
    scolb[j] = (u & 63) >> 1;
  }
  const int ldst0 = (tid & ~63) * 16;

  const ushort_t* pA0 = aBase + (size_t)srow[0] * I_DIM + scolb[0];
  const ushort_t* pA1 = aBase + (size_t)srow[1] * I_DIM + scolb[1];
  const ushort_t* pB = bBase + (size_t)srow[0] * I_DIM + scolb[0];

  int aoffV[2][4], boffV[2][4];
#pragma unroll
  for (int bq = 0; bq < 2; ++bq) {
#pragma unroll
    for (int m = 0; m < 4; ++m)
      aoffV[bq][m] = bq * 49152 + swz((wm * 64 + m * 16 + r16) * 64 + kh * 16);
#pragma unroll
    for (int n = 0; n < 4; ++n)
      boffV[bq][n] = bq * 49152 + 16384 + swz((wn * 64 + n * 16 + r16) * 64 + kh * 16);
  }

  auto stageA = [&](int buf, int ksub) {
    gload_lds16(pA0 + ksub * 32, ldsB + buf * 49152 + ksub * 24576 + ldst0);
    gload_lds16(pA1 + ksub * 32, ldsB + buf * 49152 + ksub * 24576 + 8192 + ldst0);
  };
  auto stageB = [&](int buf, int ksub) {
    gload_lds16(pB + ksub * 32, ldsB + buf * 49152 + ksub * 24576 + 16384 + ldst0);
  };
  auto rdA = [&](int buf, int ksub, int m) -> bf16x8 {
    return *(const bf16x8*)(ldsB + aoffV[buf][m] + ksub * 24576);
  };
  auto rdB = [&](int buf, int ksub, int n) -> bf16x8 {
    return *(const bf16x8*)(ldsB + boffV[buf][n] + ksub * 24576);
  };

#define G2_ADV() \
  { pA0 += 64; pA1 += 64; pB += 64; }

#define G2_TILE(CUR, NXT)                                                     \
  {                                                                           \
    _Pragma("unroll") for (int m = 0; m < 4; ++m) a[m] = rdA(CUR, 0, m);      \
    _Pragma("unroll") for (int n = 0; n < 4; ++n) b[n] = rdB(CUR, 0, n);      \
    stageA(NXT, 0);                                                           \
    stageB(NXT, 0);                                                           \
    S_BARRIER();                                                              \
    __builtin_amdgcn_s_setprio(1);                                            \
    _Pragma("unroll") for (int m = 0; m < 4; ++m)                             \
        _Pragma("unroll") for (int n = 0; n < 4; ++n)                         \
            MFMA16(acc[m][n], a[m], b[n]);                                    \
    __builtin_amdgcn_s_setprio(0);                                            \
    WAITV(3); /* ks1 units of CUR landed */                                   \
    S_BARRIER();                                                              \
    __builtin_amdgcn_sched_barrier(0);                                        \
    _Pragma("unroll") for (int m = 0; m < 4; ++m) a[m] = rdA(CUR, 1, m);      \
    _Pragma("unroll") for (int n = 0; n < 4; ++n) b[n] = rdB(CUR, 1, n);      \
    stageA(NXT, 1);                                                           \
    stageB(NXT, 1);                                                           \
    S_BARRIER();                                                              \
    __builtin_amdgcn_s_setprio(1);                                            \
    _Pragma("unroll") for (int m = 0; m < 4; ++m)                             \
        _Pragma("unroll") for (int n = 0; n < 4; ++n)                         \
            MFMA16(acc[m][n], a[m], b[n]);                                    \
    __builtin_amdgcn_s_setprio(0);                                            \
    WAITV(3); /* ks0 units of NXT landed */                                   \
    S_BARRIER();                                                              \
    __builtin_amdgcn_sched_barrier(0);                                        \
    G2_ADV();                                                                 \
  }

  // Prologue.
  stageA(0, 0); IRFENCE();
  stageB(0, 0); IRFENCE();
  stageA(0, 1); IRFENCE();
  stageB(0, 1);
  G2_ADV();
  WAITV(3);
  S_BARRIER();

  bf16x8 a[4], b[4];
#pragma unroll 1
  for (int it = 0; it < 15; ++it) {  // tiles 0..29
    G2_TILE(0, 1);
    G2_TILE(1, 0);
  }
  G2_TILE(0, 1);  // tile 30, stages 31 into buf1

  // Tail: tile 31 in buf1.
  {
#pragma unroll
    for (int m = 0; m < 4; ++m) a[m] = rdA(1, 0, m);
#pragma unroll
    for (int n = 0; n < 4; ++n) b[n] = rdB(1, 0, n);
#pragma unroll
    for (int m = 0; m < 4; ++m)
#pragma unroll
      for (int n = 0; n < 4; ++n) MFMA16(acc[m][n], a[m], b[n]);
    WAITV(0);
    S_BARRIER();
#pragma unroll
    for (int m = 0; m < 4; ++m) a[m] = rdA(1, 1, m);
#pragma unroll
    for (int n = 0; n < 4; ++n) b[n] = rdB(1, 1, n);
#pragma unroll
    for (int m = 0; m < 4; ++m)
#pragma unroll
      for (int n = 0; n < 4; ++n) MFMA16(acc[m][n], a[m], b[n]);
  }
#undef G2_TILE
#undef G2_ADV

  // Epilogue: atomic accumulate 0.5*acc into out (pre-initialized x + bias).
#pragma unroll
  for (int m = 0; m < 4; ++m)
#pragma unroll
    for (int n = 0; n < 4; ++n) {
      const int gcol = bcol + wn * 64 + n * 16 + r16;
#pragma unroll
      for (int rr = 0; rr < 4; ++rr) {
        const int grow = brow + wm * 64 + m * 16 + kh * 4 + rr;
        atomicAdd(&out[(size_t)grow * H_DIM + gcol], 0.5f * acc[m][n][rr]);
      }
    }
}

extern "C" void kernel_launch(void* const* d_in, const int* in_sizes, int n_in,
                              void* d_out, int out_size, void* d_ws, size_t ws_size,
                              hipStream_t stream) {
  const float* x = (const float*)d_in[0];
  const float* scale = (const float*)d_in[1];
  // d_in[2]=gate_kernel, d_in[3]=gate_bias: static routing, logits unused.
  const float* w1 = (const float*)d_in[4];
  const float* b1 = (const float*)d_in[5];
  const float* w2 = (const float*)d_in[6];
  const float* b2 = (const float*)d_in[7];
  float* out = (float*)d_out;

  ushort_t* ws = (ushort_t*)d_ws;
  ushort_t* normed = ws;                                    // [T][H]
  ushort_t* w1T = normed + (size_t)T_DIM * H_DIM;           // [2][2I][H]
  ushort_t* w2T = w1T + (size_t)2 * 2 * I_DIM * H_DIM;      // [2][H][I]
  ushort_t* actb = w2T + (size_t)2 * H_DIM * I_DIM;         // [2][T][I]

  k_rmsnorm_init<<<dim3(T_DIM), 256, 0, stream>>>(x, scale, b2, normed, out);
  k_transpose_cvt<<<dim3(2 * I_DIM / 32, H_DIM / 32, 2), 256, 0, stream>>>(
      w1, w1T, H_DIM, 2 * I_DIM);
  k_transpose_cvt<<<dim3(H_DIM / 32, I_DIM / 32, 2), 256, 0, stream>>>(
      w2, w2T, I_DIM, H_DIM);
  k_gemm1_8ph<<<dim3(512), 512, 0, stream>>>(normed, w1T, b1, actb);
  k_gemm2_8ph<<<dim3(256), 512, 0, stream>>>(actb, w2T, out);
}

// Round 6
// 149.231 us; speedup vs baseline: 1.1958x; 1.0043x over previous
//
#include <hip/hip_runtime.h>
#include <hip/hip_bf16.h>
#include <stdint.h>

#define T_DIM 4096
#define H_DIM 1024
#define I_DIM 2048

typedef __bf16 bf16x8 __attribute__((ext_vector_type(8)));
typedef float f32x4 __attribute__((ext_vector_type(4)));
typedef unsigned short ushort_t;
typedef unsigned short us4 __attribute__((ext_vector_type(4)));

__device__ __forceinline__ unsigned short f32_to_bf16(float f) {
  unsigned int u = __float_as_uint(f);
  u += 0x7fffu + ((u >> 16) & 1u);  // RNE
  return (unsigned short)(u >> 16);
}

__device__ __forceinline__ void gload_lds16(const void* g, void* l) {
  __builtin_amdgcn_global_load_lds(
      (__attribute__((address_space(1))) void*)(uintptr_t)g,
      (__attribute__((address_space(3))) void*)(unsigned int)(uintptr_t)l,
      16, 0, 0);
}

// XOR swizzle on byte offsets within a 16KB unit (involution; key bits 7-9
// untouched). Verified R4: SQ_LDS_BANK_CONFLICT 6.29M -> 0.
__device__ __forceinline__ int swz(int L) { return L ^ (((L >> 7) & 7) << 4); }

#define S_BARRIER() asm volatile("s_barrier" ::: "memory")
#define WAITV(n) asm volatile("s_waitcnt vmcnt(" #n ")" ::: "memory")
#define IRFENCE() asm volatile("" ::: "memory")
#define MFMA16(acc, va, vb) \
  acc = __builtin_amdgcn_mfma_f32_16x16x32_bf16(va, vb, acc, 0, 0, 0)

// ------- rmsnorm + out-init fused ---------------------------------------------
__global__ __launch_bounds__(256) void k_rmsnorm_init(
    const float* __restrict__ x, const float* __restrict__ scale,
    const float* __restrict__ b2, ushort_t* __restrict__ normed,
    float* __restrict__ out) {
  const int row = blockIdx.x, tid = threadIdx.x;
  const float4 v = ((const float4*)(x + (size_t)row * H_DIM))[tid];
  float ss = v.x * v.x + v.y * v.y + v.z * v.z + v.w * v.w;
#pragma unroll
  for (int off = 32; off > 0; off >>= 1) ss += __shfl_xor(ss, off);
  __shared__ float wsum[4];
  if ((tid & 63) == 0) wsum[tid >> 6] = ss;
  __syncthreads();
  const float tot = wsum[0] + wsum[1] + wsum[2] + wsum[3];
  const float inv = rsqrtf(tot * (1.0f / H_DIM) + 1e-5f);
  const float4 sc = ((const float4*)scale)[tid];
  us4 o;
  o.x = f32_to_bf16(v.x * inv * sc.x);
  o.y = f32_to_bf16(v.y * inv * sc.y);
  o.z = f32_to_bf16(v.z * inv * sc.z);
  o.w = f32_to_bf16(v.w * inv * sc.w);
  ((us4*)(normed + (size_t)row * H_DIM))[tid] = o;
  const float4 b0 = ((const float4*)b2)[tid];
  const float4 b1 = ((const float4*)(b2 + H_DIM))[tid];
  float4 ov;
  ov.x = v.x + 0.5f * (b0.x + b1.x);
  ov.y = v.y + 0.5f * (b0.y + b1.y);
  ov.z = v.z + 0.5f * (b0.z + b1.z);
  ov.w = v.w + 0.5f * (b0.w + b1.w);
  ((float4*)(out + (size_t)row * H_DIM))[tid] = ov;
}

// ------- transpose+convert: src[R][C] f32 -> dst[C][R] bf16 (per blockIdx.z) ---
__global__ __launch_bounds__(256) void k_transpose_cvt(const float* __restrict__ src,
                                                       ushort_t* __restrict__ dst,
                                                       int R, int C) {
  __shared__ float tile[32][33];
  const size_t eoff = (size_t)blockIdx.z * (size_t)R * (size_t)C;
  src += eoff;
  dst += eoff;
  const int x0 = blockIdx.x * 32, y0 = blockIdx.y * 32;
  const int tx = threadIdx.x & 31, ty = threadIdx.x >> 5;
#pragma unroll
  for (int i = 0; i < 4; ++i)
    tile[ty + 8 * i][tx] = src[(size_t)(y0 + ty + 8 * i) * C + x0 + tx];
  __syncthreads();
#pragma unroll
  for (int i = 0; i < 4; ++i)
    dst[(size_t)(x0 + ty + 8 * i) * R + y0 + tx] = f32_to_bf16(tile[tx][ty + 8 * i]);
}

// ---------------- GEMM1: 256x(128g+128l), BK=64, 8 waves, 2 barriers/K-tile ----
// The ONLY load-bearing sync: WAITV(4)+S_BARRIER at each K-half boundary
// (drains the K-half unit staged one tile ago; counts identical to verified R4).
// All alignment-only barriers removed -> waves free-run, LDS reads overlap MFMA.
__global__ __launch_bounds__(512, 2) void k_gemm1_8ph(
    const ushort_t* __restrict__ normed, const ushort_t* __restrict__ w1T,
    const float* __restrict__ b1, ushort_t* __restrict__ act) {
  __shared__ __align__(16) ushort_t lds[2][4][8192];  // 128 KiB
  char* const ldsB = (char*)&lds[0][0][0];
  const int tid = threadIdx.x;
  const int wg = (blockIdx.x & 7) * 64 + (blockIdx.x >> 3);  // XCD swizzle
  const int e = wg >> 8;
  const int rem = wg & 255;
  const int brow = (rem >> 4) * 256;
  const int bcol = (rem & 15) * 128;
  const int lane = tid & 63;
  const int wm = (tid >> 6) >> 1;
  const int wn = (tid >> 6) & 1;
  const int r16 = lane & 15, kh = lane >> 4;

  const ushort_t* aBase = normed + (size_t)brow * H_DIM;
  const ushort_t* gBase = w1T + ((size_t)e * 2 * I_DIM + bcol) * H_DIM;
  const ushort_t* lBase = gBase + (size_t)I_DIM * H_DIM;

  f32x4 accg[4][4], accl[4][4];
  const f32x4 zf = {0.f, 0.f, 0.f, 0.f};
#pragma unroll
  for (int m = 0; m < 4; ++m)
#pragma unroll
    for (int n = 0; n < 4; ++n) { accg[m][n] = zf; accl[m][n] = zf; }

  int srow[2], scolb[2];
#pragma unroll
  for (int j = 0; j < 2; ++j) {
    const int u = swz((j * 512 + tid) * 16);
    srow[j] = u >> 6;
    scolb[j] = (u & 63) >> 1;
  }
  const int ldst0 = (tid & ~63) * 16;

  const ushort_t* pA0 = aBase + (size_t)srow[0] * H_DIM + scolb[0];
  const ushort_t* pA1 = aBase + (size_t)srow[1] * H_DIM + scolb[1];
  const ushort_t* pG = gBase + (size_t)srow[0] * H_DIM + scolb[0];
  const ushort_t* pL = lBase + (size_t)(srow[1] - 128) * H_DIM + scolb[1];

  int aoffV[2][4], boffV[2][4];
#pragma unroll
  for (int bq = 0; bq < 2; ++bq) {
#pragma unroll
    for (int m = 0; m < 4; ++m)
      aoffV[bq][m] = bq * 65536 + swz((wm * 64 + m * 16 + r16) * 64 + kh * 16);
#pragma unroll
    for (int n = 0; n < 4; ++n)
      boffV[bq][n] = bq * 65536 + 16384 + swz((wn * 64 + n * 16 + r16) * 64 + kh * 16);
  }

  auto stageA = [&](int buf, int ksub) {
    gload_lds16(pA0 + ksub * 32, ldsB + buf * 65536 + ksub * 32768 + ldst0);
    gload_lds16(pA1 + ksub * 32, ldsB + buf * 65536 + ksub * 32768 + 8192 + ldst0);
  };
  auto stageB = [&](int buf, int ksub) {
    gload_lds16(pG + ksub * 32, ldsB + buf * 65536 + ksub * 32768 + 16384 + ldst0);
    gload_lds16(pL + ksub * 32, ldsB + buf * 65536 + ksub * 32768 + 16384 + 8192 + ldst0);
  };
  auto rdA = [&](int buf, int ksub, int m) -> bf16x8 {
    return *(const bf16x8*)(ldsB + aoffV[buf][m] + ksub * 32768);
  };
  auto rdBg = [&](int buf, int ksub, int n) -> bf16x8 {
    return *(const bf16x8*)(ldsB + boffV[buf][n] + ksub * 32768);
  };
  auto rdBl = [&](int buf, int ksub, int n) -> bf16x8 {
    return *(const bf16x8*)(ldsB + boffV[buf][n] + ksub * 32768 + 8192);
  };

#define G1_ADV() \
  { pA0 += 64; pA1 += 64; pG += 64; pL += 64; }

  // One K-half: 8+4 ds_reads, 4 stage loads, 32 MFMA, then the single
  // load-bearing WAITV(4)+barrier. No other barriers.
#define G1_HALF(CUR, NXT, KS)                                                 \
  {                                                                           \
    _Pragma("unroll") for (int m = 0; m < 4; ++m) a[m] = rdA(CUR, KS, m);     \
    _Pragma("unroll") for (int n = 0; n < 4; ++n) b[n] = rdBg(CUR, KS, n);    \
    stageA(NXT, KS);                                                          \
    stageB(NXT, KS);                                                          \
    __builtin_amdgcn_s_setprio(1);                                            \
    _Pragma("unroll") for (int m = 0; m < 4; ++m)                             \
        _Pragma("unroll") for (int n = 0; n < 4; ++n)                         \
            MFMA16(accg[m][n], a[m], b[n]);                                   \
    __builtin_amdgcn_s_setprio(0);                                            \
    _Pragma("unroll") for (int n = 0; n < 4; ++n) b[n] = rdBl(CUR, KS, n);    \
    __builtin_amdgcn_s_setprio(1);                                            \
    _Pragma("unroll") for (int m = 0; m < 4; ++m)                             \
        _Pragma("unroll") for (int n = 0; n < 4; ++n)                         \
            MFMA16(accl[m][n], a[m], b[n]);                                   \
    __builtin_amdgcn_s_setprio(0);                                            \
    WAITV(4);                                                                 \
    S_BARRIER();                                                              \
  }

#define G1_TILE(CUR, NXT)  \
  { G1_HALF(CUR, NXT, 0); G1_HALF(CUR, NXT, 1); G1_ADV(); }

  // Prologue: stage tile 0 (half order pinned), advance to tile 1.
  stageA(0, 0); stageB(0, 0); IRFENCE();
  stageA(0, 1); stageB(0, 1);
  G1_ADV();
  WAITV(4);  // half 0 of tile 0 landed; half 1 (4 loads) stays in flight
  S_BARRIER();

  bf16x8 a[4], b[4];
#pragma unroll 1
  for (int it = 0; it < 7; ++it) {  // tiles 0..13
    G1_TILE(0, 1);
    G1_TILE(1, 0);
  }
  G1_TILE(0, 1);  // tile 14, stages tile 15 into buf1

  // Tail: tile 15 in buf1 (half0 drained by tile14's last WAITV; half1 in flight).
  {
#pragma unroll
    for (int m = 0; m < 4; ++m) a[m] = rdA(1, 0, m);
#pragma unroll
    for (int n = 0; n < 4; ++n) b[n] = rdBg(1, 0, n);
#pragma unroll
    for (int m = 0; m < 4; ++m)
#pragma unroll
      for (int n = 0; n < 4; ++n) MFMA16(accg[m][n], a[m], b[n]);
#pragma unroll
    for (int n = 0; n < 4; ++n) b[n] = rdBl(1, 0, n);
#pragma unroll
    for (int m = 0; m < 4; ++m)
#pragma unroll
      for (int n = 0; n < 4; ++n) MFMA16(accl[m][n], a[m], b[n]);
    WAITV(0);
    S_BARRIER();  // all waves' half-1 staging drained
#pragma unroll
    for (int m = 0; m < 4; ++m) a[m] = rdA(1, 1, m);
#pragma unroll
    for (int n = 0; n < 4; ++n) b[n] = rdBg(1, 1, n);
#pragma unroll
    for (int m = 0; m < 4; ++m)
#pragma unroll
      for (int n = 0; n < 4; ++n) MFMA16(accg[m][n], a[m], b[n]);
#pragma unroll
    for (int n = 0; n < 4; ++n) b[n] = rdBl(1, 1, n);
#pragma unroll
    for (int m = 0; m < 4; ++m)
#pragma unroll
      for (int n = 0; n < 4; ++n) MFMA16(accl[m][n], a[m], b[n]);
  }
#undef G1_HALF
#undef G1_TILE
#undef G1_ADV

  // Epilogue: bias + clip + sigmoid-gate, store bf16 act.
  const float* b1e = b1 + (size_t)e * 2 * I_DIM;
#pragma unroll
  for (int m = 0; m < 4; ++m)
#pragma unroll
    for (int n = 0; n < 4; ++n) {
      const int gcol = bcol + wn * 64 + n * 16 + r16;
      const float bgb = b1e[gcol];
      const float blb = b1e[I_DIM + gcol];
#pragma unroll
      for (int rr = 0; rr < 4; ++rr) {
        const int grow = brow + wm * 64 + m * 16 + kh * 4 + rr;
        const float hg = accg[m][n][rr] + bgb;
        const float hl = accl[m][n][rr] + blb;
        const float g = fminf(hg, 7.f);
        const float l = fminf(fmaxf(hl, -7.f), 7.f);
        const float s = 1.f / (1.f + __expf(-1.702f * g));
        const float av = g * s * (l + 1.f);
        act[((size_t)e * T_DIM + grow) * I_DIM + gcol] = f32_to_bf16(av);
      }
    }
}

// ---------------- GEMM2: 256x128, split-K=2 (expert), 2 barriers/K-tile -------
__global__ __launch_bounds__(512, 2) void k_gemm2_8ph(
    const ushort_t* __restrict__ act, const ushort_t* __restrict__ w2T,
    float* __restrict__ out) {
  __shared__ __align__(16) ushort_t lds[2][2][12288];  // 96 KiB
  char* const ldsB = (char*)&lds[0][0][0];
  const int tid = threadIdx.x;
  const int wg = (blockIdx.x & 7) * 32 + (blockIdx.x >> 3);
  const int e = wg >> 7;
  const int tileid = wg & 127;
  const int brow = (tileid >> 3) * 256;
  const int bcol = (tileid & 7) * 128;
  const int lane = tid & 63;
  const int wm = (tid >> 6) >> 1;
  const int wn = (tid >> 6) & 1;
  const int r16 = lane & 15, kh = lane >> 4;

  const ushort_t* aBase = act + ((size_t)e * T_DIM + brow) * I_DIM;
  const ushort_t* bBase = w2T + ((size_t)e * H_DIM + bcol) * I_DIM;

  f32x4 acc[4][4];
  const f32x4 zf = {0.f, 0.f, 0.f, 0.f};
#pragma unroll
  for (int m = 0; m < 4; ++m)
#pragma unroll
    for (int n = 0; n < 4; ++n) acc[m][n] = zf;

  int srow[2], scolb[2];
#pragma unroll
  for (int j = 0; j < 2; ++j) {
    const int u = swz((j * 512 + tid) * 16);
    srow[j] = u >> 6;
    scolb[j] = (u & 63) >> 1;
  }
  const int ldst0 = (tid & ~63) * 16;

  const ushort_t* pA0 = aBase + (size_t)srow[0] * I_DIM + scolb[0];
  const ushort_t* pA1 = aBase + (size_t)srow[1] * I_DIM + scolb[1];
  const ushort_t* pB = bBase + (size_t)srow[0] * I_DIM + scolb[0];

  int aoffV[2][4], boffV[2][4];
#pragma unroll
  for (int bq = 0; bq < 2; ++bq) {
#pragma unroll
    for (int m = 0; m < 4; ++m)
      aoffV[bq][m] = bq * 49152 + swz((wm * 64 + m * 16 + r16) * 64 + kh * 16);
#pragma unroll
    for (int n = 0; n < 4; ++n)
      boffV[bq][n] = bq * 49152 + 16384 + swz((wn * 64 + n * 16 + r16) * 64 + kh * 16);
  }

  auto stageA = [&](int buf, int ksub) {
    gload_lds16(pA0 + ksub * 32, ldsB + buf * 49152 + ksub * 24576 + ldst0);
    gload_lds16(pA1 + ksub * 32, ldsB + buf * 49152 + ksub * 24576 + 8192 + ldst0);
  };
  auto stageB = [&](int buf, int ksub) {
    gload_lds16(pB + ksub * 32, ldsB + buf * 49152 + ksub * 24576 + 16384 + ldst0);
  };
  auto rdA = [&](int buf, int ksub, int m) -> bf16x8 {
    return *(const bf16x8*)(ldsB + aoffV[buf][m] + ksub * 24576);
  };
  auto rdB = [&](int buf, int ksub, int n) -> bf16x8 {
    return *(const bf16x8*)(ldsB + boffV[buf][n] + ksub * 24576);
  };

#define G2_ADV() \
  { pA0 += 64; pA1 += 64; pB += 64; }

#define G2_HALF(CUR, NXT, KS)                                                 \
  {                                                                           \
    _Pragma("unroll") for (int m = 0; m < 4; ++m) a[m] = rdA(CUR, KS, m);     \
    _Pragma("unroll") for (int n = 0; n < 4; ++n) b[n] = rdB(CUR, KS, n);     \
    stageA(NXT, KS);                                                          \
    stageB(NXT, KS);                                                          \
    __builtin_amdgcn_s_setprio(1);                                            \
    _Pragma("unroll") for (int m = 0; m < 4; ++m)                             \
        _Pragma("unroll") for (int n = 0; n < 4; ++n)                         \
            MFMA16(acc[m][n], a[m], b[n]);                                    \
    __builtin_amdgcn_s_setprio(0);                                            \
    WAITV(3);                                                                 \
    S_BARRIER();                                                              \
  }

#define G2_TILE(CUR, NXT)  \
  { G2_HALF(CUR, NXT, 0); G2_HALF(CUR, NXT, 1); G2_ADV(); }

  // Prologue.
  stageA(0, 0); stageB(0, 0); IRFENCE();
  stageA(0, 1); stageB(0, 1);
  G2_ADV();
  WAITV(3);
  S_BARRIER();

  bf16x8 a[4], b[4];
#pragma unroll 1
  for (int it = 0; it < 15; ++it) {  // tiles 0..29
    G2_TILE(0, 1);
    G2_TILE(1, 0);
  }
  G2_TILE(0, 1);  // tile 30, stages 31 into buf1

  // Tail: tile 31 in buf1.
  {
#pragma unroll
    for (int m = 0; m < 4; ++m) a[m] = rdA(1, 0, m);
#pragma unroll
    for (int n = 0; n < 4; ++n) b[n] = rdB(1, 0, n);
#pragma unroll
    for (int m = 0; m < 4; ++m)
#pragma unroll
      for (int n = 0; n < 4; ++n) MFMA16(acc[m][n], a[m], b[n]);
    WAITV(0);
    S_BARRIER();
#pragma unroll
    for (int m = 0; m < 4; ++m) a[m] = rdA(1, 1, m);
#pragma unroll
    for (int n = 0; n < 4; ++n) b[n] = rdB(1, 1, n);
#pragma unroll
    for (int m = 0; m < 4; ++m)
#pragma unroll
      for (int n = 0; n < 4; ++n) MFMA16(acc[m][n], a[m], b[n]);
  }
#undef G2_HALF
#undef G2_TILE
#undef G2_ADV

  // Epilogue: atomic accumulate 0.5*acc into out (pre-initialized x + bias).
#pragma unroll
  for (int m = 0; m < 4; ++m)
#pragma unroll
    for (int n = 0; n < 4; ++n) {
      const int gcol = bcol + wn * 64 + n * 16 + r16;
#pragma unroll
      for (int rr = 0; rr < 4; ++rr) {
        const int grow = brow + wm * 64 + m * 16 + kh * 4 + rr;
        atomicAdd(&out[(size_t)grow * H_DIM + gcol], 0.5f * acc[m][n][rr]);
      }
    }
}

extern "C" void kernel_launch(void* const* d_in, const int* in_sizes, int n_in,
                              void* d_out, int out_size, void* d_ws, size_t ws_size,
                              hipStream_t stream) {
  const float* x = (const float*)d_in[0];
  const float* scale = (const float*)d_in[1];
  // d_in[2]=gate_kernel, d_in[3]=gate_bias: static routing, logits unused.
  const float* w1 = (const float*)d_in[4];
  const float* b1 = (const float*)d_in[5];
  const float* w2 = (const float*)d_in[6];
  const float* b2 = (const float*)d_in[7];
  float* out = (float*)d_out;

  ushort_t* ws = (ushort_t*)d_ws;
  ushort_t* normed = ws;                                    // [T][H]
  ushort_t* w1T = normed + (size_t)T_DIM * H_DIM;           // [2][2I][H]
  ushort_t* w2T = w1T + (size_t)2 * 2 * I_DIM * H_DIM;      // [2][H][I]
  ushort_t* actb = w2T + (size_t)2 * H_DIM * I_DIM;         // [2][T][I]

  k_rmsnorm_init<<<dim3(T_DIM), 256, 0, stream>>>(x, scale, b2, normed, out);
  k_transpose_cvt<<<dim3(2 * I_DIM / 32, H_DIM / 32, 2), 256, 0, stream>>>(
      w1, w1T, H_DIM, 2 * I_DIM);
  k_transpose_cvt<<<dim3(H_DIM / 32, I_DIM / 32, 2), 256, 0, stream>>>(
      w2, w2T, I_DIM, H_DIM);
  k_gemm1_8ph<<<dim3(512), 512, 0, stream>>>(normed, w1T, b1, actb);
  k_gemm2_8ph<<<dim3(256), 512, 0, stream>>>(actb, w2T, out);
}